// Round 13
// baseline (6701.239 us; speedup 1.0000x reference)
//
#include <hip/hip_runtime.h>

typedef unsigned short ushort_t;
typedef unsigned long long u64;
typedef __attribute__((ext_vector_type(4))) float f32x4;
typedef __attribute__((ext_vector_type(8))) __bf16 bf16x8;

#define SEQ   512
#define BATCH 128
#define HID   1024
#define G4    4096
#define CHUNK 64
#define BH    (BATCH*HID)
#define NBLK  256
#define SCAN_LDS (131072 + 32768)
#define GEMM256_LDS 131072
#define HXATOMS 65536                 // 128 rows x 512 atoms (8B each) per buffer

__device__ __forceinline__ ushort_t f2bf(float f) {
  unsigned u = __float_as_uint(f);
  u += 0x7FFFu + ((u >> 16) & 1u);         // RNE
  return (ushort_t)(u >> 16);
}
__device__ __forceinline__ float bf2f(ushort_t h) {
  return __uint_as_float(((unsigned)h) << 16);
}
__device__ __forceinline__ float sigm(float x) { return 1.0f / (1.0f + __expf(-x)); }
__device__ __forceinline__ float ftanh(float x) {
  float xc = fminf(fmaxf(x, -15.f), 15.f);
  float t = __expf(2.f * xc);
  return (t - 1.f) / (t + 1.f);
}

__device__ __forceinline__ void lds16(const ushort_t* g, ushort_t* l) {
  __builtin_amdgcn_global_load_lds(
      (const __attribute__((address_space(1))) unsigned int*)g,
      (__attribute__((address_space(3))) unsigned int*)l, 16, 0, 0);
}

// ---------------- casts ----------------
__global__ void cast_f32_bf16(const float* __restrict__ in, ushort_t* __restrict__ out, int n4) {
  int i = blockIdx.x * blockDim.x + threadIdx.x;
  if (i < n4) {
    float4 v = ((const float4*)in)[i];
    union { ushort_t u[4]; uint2 v2; } o;
    o.u[0] = f2bf(v.x); o.u[1] = f2bf(v.y); o.u[2] = f2bf(v.z); o.u[3] = f2bf(v.w);
    ((uint2*)out)[i] = o.v2;
  }
}

__global__ __launch_bounds__(256) void transpose_cast(const float* __restrict__ pw, ushort_t* __restrict__ pwt) {
  __shared__ float tile[32][33];
  int bx = blockIdx.x, by = blockIdx.y;
  int tx = threadIdx.x & 31, ty = threadIdx.x >> 5;
  for (int i = 0; i < 32; i += 8)
    tile[ty + i][tx] = pw[(size_t)(by*32 + ty + i)*2048 + bx*32 + tx];
  __syncthreads();
  for (int i = 0; i < 32; i += 8) {
    int r = ty + i;
    pwt[(size_t)(bx*32 + r)*4096 + by*32 + tx] = f2bf(tile[tx][r]);
  }
}

__global__ void bias_fold(const float* __restrict__ qW, const float* __restrict__ pb, float* __restrict__ b2) {
  int r = blockIdx.x;
  int j = r & (HID-1), gb = r & ~(HID-1);
  float s = 0.f;
  for (int k = threadIdx.x; k < HID; k += 64)
    s += qW[(size_t)j*HID + k] * pb[gb + k];
  for (int off = 32; off; off >>= 1) s += __shfl_down(s, off, 64);
  if (threadIdx.x == 0) b2[r] = s;
}

// ---------------- 128x128 bf16 GEMM (m97 structure) — weight fold only
__global__ __launch_bounds__(256) void gemm128(
    const ushort_t* __restrict__ A, int lda, unsigned arow_mask,
    const ushort_t* __restrict__ B, int ldb, unsigned bko_mask,
    const float* __restrict__ bias, ushort_t* __restrict__ C, int ldc, int K)
{
  __shared__ __align__(16) ushort_t Al[128*64];
  __shared__ __align__(16) ushort_t Bl[128*64];
  const int tid = threadIdx.x, wv = tid >> 6, ln = tid & 63;
  const int bn = blockIdx.x, bm = blockIdx.y;
  const int bko = (int)(((unsigned)(bm << 7)) & bko_mask);
  const int m0 = (wv & 1) << 6, n0 = (wv >> 1) << 6;
  f32x4 acc[4][4] = {};
  for (int k0 = 0; k0 < K; k0 += 64) {
    for (int rr = 0; rr < 4; ++rr) {
      int r0 = (rr << 5) + (wv << 3);
      unsigned ga = ((unsigned)((bm << 7) + r0 + (ln >> 3))) & arow_mask;
      lds16(A + (size_t)ga*lda + k0 + ((ln & 7) << 3), &Al[r0 << 6]);
      unsigned gbr = (unsigned)((bn << 7) + r0 + (ln >> 3));
      lds16(B + (size_t)gbr*ldb + bko + k0 + ((ln & 7) << 3), &Bl[r0 << 6]);
    }
    __syncthreads();
    for (int kk = 0; kk < 64; kk += 32) {
      const int lrow = ln & 15, lk = kk + ((ln >> 4) << 3);
      bf16x8 af[4], bfr[4];
      for (int i = 0; i < 4; ++i) af[i]  = *(const bf16x8*)&Al[((m0 + (i << 4) + lrow) << 6) + lk];
      for (int j = 0; j < 4; ++j) bfr[j] = *(const bf16x8*)&Bl[((n0 + (j << 4) + lrow) << 6) + lk];
      for (int i = 0; i < 4; ++i)
        for (int j = 0; j < 4; ++j)
          acc[i][j] = __builtin_amdgcn_mfma_f32_16x16x32_bf16(af[i], bfr[j], acc[i][j], 0, 0, 0);
    }
    __syncthreads();
  }
  for (int i = 0; i < 4; ++i)
    for (int j = 0; j < 4; ++j) {
      int col = (bn << 7) + n0 + (j << 4) + (ln & 15);
      float bv = bias ? bias[col] : 0.f;
      for (int r = 0; r < 4; ++r) {
        int row = (bm << 7) + m0 + (i << 4) + ((ln >> 4) << 2) + r;
        C[(size_t)row*ldc + col] = f2bf(acc[i][j][r] + bv);
      }
    }
}

// ---------------- 256x256 8-phase bf16 GEMM: P = x @ V^T + b2 (r10-verified) ----
__global__ __launch_bounds__(512) void gemm256(
    const ushort_t* __restrict__ A, const ushort_t* __restrict__ B,
    const float* __restrict__ bias, ushort_t* __restrict__ C)
{
  extern __shared__ __align__(16) ushort_t lds[];
  ushort_t* LA = lds;
  ushort_t* LB = lds + 32768;
  const int tid = threadIdx.x, wv8 = tid >> 6, ln = tid & 63;
  const int wm = wv8 >> 2, wn = wv8 & 3;
  const int flat = blockIdx.y * gridDim.x + blockIdx.x;     // 0..511
  const int swz  = ((flat & 7) << 6) | (flat >> 3);          // bijective
  const int bn = swz & 15, bm = swz >> 4;
  const int lr = ln & 15, lg = ln >> 4;

  f32x4 acc[8][4] = {};
  bf16x8 af[4][2], bfr[4][2];

  auto stA = [&](int db, int half, int kt) {
    ushort_t* d = LA + db*16384 + half*8192 + (wv8 << 9);
    const int ce = ((ln & 7) ^ (ln >> 3)) << 3;
    #pragma unroll
    for (int p = 0; p < 2; ++p) {
      int rr = half*128 + p*64 + (wv8 << 3) + (ln >> 3);
      lds16(A + (size_t)(bm*256 + rr)*1024 + kt*64 + ce, d + p*4096);
    }
  };
  auto stB = [&](int db, int half, int kt) {
    ushort_t* d = LB + db*16384 + half*8192 + (wv8 << 9);
    const int ce = ((ln & 7) ^ (ln >> 3)) << 3;
    #pragma unroll
    for (int p = 0; p < 2; ++p) {
      int rr = half*128 + p*64 + (wv8 << 3) + (ln >> 3);
      lds16(B + (size_t)(bn*256 + rr)*2048 + kt*64 + ce, d + p*4096);
    }
  };

#define RD_A(DB, MQ) { _Pragma("unroll") for (int i_ = 0; i_ < 4; ++i_) { \
    const int row_ = ((MQ)*4 + i_)*16 + lr; \
    const ushort_t* b_ = &LA[(DB)*16384 + wm*8192 + row_*64]; \
    af[i_][0] = *(const bf16x8*)&b_[ (lg << 3)       ^ ((lr & 7) << 3)]; \
    af[i_][1] = *(const bf16x8*)&b_[((lg << 3) | 32) ^ ((lr & 7) << 3)]; } }

#define RD_B(DB, NQ) { _Pragma("unroll") for (int j_ = 0; j_ < 2; ++j_) { \
    const int row_ = (wn & 1)*64 + ((NQ)*2 + j_)*16 + lr; \
    const ushort_t* b_ = &LB[(DB)*16384 + (wn >> 1)*8192 + row_*64]; \
    bfr[(NQ)*2 + j_][0] = *(const bf16x8*)&b_[ (lg << 3)       ^ ((lr & 7) << 3)]; \
    bfr[(NQ)*2 + j_][1] = *(const bf16x8*)&b_[((lg << 3) | 32) ^ ((lr & 7) << 3)]; } }

#define QUAD(MQ, NQ) \
  __builtin_amdgcn_s_setprio(1); \
  { _Pragma("unroll") for (int i_ = 0; i_ < 4; ++i_) \
      _Pragma("unroll") for (int j_ = 0; j_ < 2; ++j_) \
        _Pragma("unroll") for (int k_ = 0; k_ < 2; ++k_) \
          acc[(MQ)*4 + i_][(NQ)*2 + j_] = __builtin_amdgcn_mfma_f32_16x16x32_bf16( \
              af[i_][k_], bfr[(NQ)*2 + j_][k_], acc[(MQ)*4 + i_][(NQ)*2 + j_], 0, 0, 0); } \
  __builtin_amdgcn_s_setprio(0);

#define BAR() __builtin_amdgcn_s_barrier()
#define LGK0() do { asm volatile("s_waitcnt lgkmcnt(0)" ::: "memory"); \
                    __builtin_amdgcn_sched_barrier(0); } while (0)
#define VM4() do { asm volatile("s_waitcnt vmcnt(4)" ::: "memory"); \
                   __builtin_amdgcn_sched_barrier(0); } while (0)

  stA(0,0,0); stA(0,1,0); stB(0,0,0); stB(0,1,0); stB(1,0,1); stB(1,1,1);
  asm volatile("s_waitcnt vmcnt(4)" ::: "memory");
  BAR();

  for (int i = 0; i < 8; ++i) {
    const int k1 = 2*i + 1, k2 = 2*i + 2, k3 = 2*i + 3;
    RD_A(0,0); RD_B(0,0); stA(1,0,k1);            BAR(); LGK0(); QUAD(0,0); BAR();
    RD_B(0,1); stA(1,1,k1);                       BAR(); LGK0(); QUAD(0,1); BAR();
    RD_A(0,1); if (k2 < 16) stB(0,0,k2);          BAR(); LGK0(); QUAD(1,0); BAR();
    if (k2 < 16) stB(0,1,k2);                     BAR();         QUAD(1,1); VM4(); BAR();
    RD_A(1,0); RD_B(1,0); if (k2 < 16) stA(0,0,k2); BAR(); LGK0(); QUAD(0,0); BAR();
    RD_B(1,1); if (k2 < 16) stA(0,1,k2);          BAR(); LGK0(); QUAD(0,1); BAR();
    RD_A(1,1); if (k3 < 16) stB(1,0,k3);          BAR(); LGK0(); QUAD(1,0); BAR();
    if (k3 < 16) stB(1,1,k3);                     BAR();         QUAD(1,1); VM4(); BAR();
  }

  const int crow0 = bm*256 + wm*128;
  const int ccol0 = bn*256 + wn*64;
  #pragma unroll
  for (int m = 0; m < 8; ++m)
    #pragma unroll
    for (int n = 0; n < 4; ++n) {
      int col = ccol0 + n*16 + lr;
      float bv = bias[col];
      #pragma unroll
      for (int r = 0; r < 4; ++r) {
        int row = crow0 + m*16 + lg*4 + r;
        C[(size_t)row*4096 + col] = f2bf(acc[m][n][r] + bv);
      }
    }
#undef RD_A
#undef RD_B
#undef QUAD
#undef BAR
#undef LGK0
#undef VM4
}

// ---------------- persistent per-chunk scan: tagged-atom hx exchange ----------
// 256 blocks (1/CU). rblk = bid&3 (32 hx rows), cblk = bid>>2 (16 cols x 4 gates).
// hx atom (8B) = {h[2col] bf16x2, step tag}. Producers store atoms with agent
// atomics (no drain/flag/poll); consumers reg-stage + verify tag + ds_write.
__global__ __launch_bounds__(256, 1) void qlstm_scan(
    const ushort_t* __restrict__ P,      // [CHUNK*128][4096] bf16
    const ushort_t* __restrict__ W2,     // [4096][2048] bf16; U = cols [1024,2048)
    u64* __restrict__ hx2,               // 3 buffers x [128 rows][512 atoms]
    float* __restrict__ cxg,             // [128][1024] f32 (chunk handoff)
    float* __restrict__ outc,            // d_out + c*CHUNK*BH
    int t0)
{
  extern __shared__ __align__(16) ushort_t lds[];
  ushort_t* Ul = lds;                    // [8 ck][64 rows][128] swizzled, 128 KB
  ushort_t* Ar = lds + 65536;            // 4 slots x [32][128], 32 KB
  float*    sm = (float*)(lds + 65536);  // aliases Ar slot0 (epilogue only)

  const int tid = threadIdx.x, wv = tid >> 6, ln = tid & 63;
  const int rblk = blockIdx.x & 3, cblk = blockIdx.x >> 2;

  // ---- stage resident U once (64 rows x K=1024), chunk-major, XOR-swizzled src
  for (int ck = 0; ck < 8; ++ck)
    for (int rr = 0; rr < 4; ++rr) {
      int lrw = rr*16 + wv*4 + (ln >> 4);
      int grow = ((lrw >> 4) << 10) + cblk*16 + (lrw & 15);
      int gcol = ck*128 + (((ln & 15) ^ (lrw & 7)) << 3);
      lds16(W2 + (size_t)grow*2048 + 1024 + gcol, &Ul[ck*8192 + (rr*16 + wv*4)*128]);
    }

  // ---- epilogue slice: row b_loc, adjacent cols j0,j0+1 (one 8B atom)
  const int b_loc = tid >> 3;
  const int j0    = (tid & 7) << 1;
  const size_t ci = (size_t)(rblk*32 + b_loc)*1024 + cblk*16 + j0;
  const size_t catom = (size_t)(rblk*32 + b_loc)*512 + cblk*8 + (j0 >> 1);
  float2 cxr = *(const float2*)&cxg[ci];

  // ---- consumer stage geometry (matches old lds16c lane-linear layout)
  const int p15 = ln & 15;
  const int r0l = wv*4 + (ln >> 4);          // local rows 0..15 / 16..31
  const int r1l = 16 + r0l;
  const int gc0 = (p15 ^ (r0l & 7)) << 3;    // XOR-swizzled element col
  const int gc1 = (p15 ^ (r1l & 7)) << 3;
  const size_t ab0 = (size_t)(rblk*32 + r0l)*512 + (gc0 >> 1);
  const size_t ab1 = (size_t)(rblk*32 + r1l)*512 + (gc1 >> 1);
  const int ldo0 = r0l*128 + p15*8;          // LDS elem offsets
  const int ldo1 = r1l*128 + p15*8;

  auto load_pv = [&](int tl, float* pv) {
    #pragma unroll
    for (int i = 0; i < 2; ++i)
      #pragma unroll
      for (int r = 0; r < 4; ++r) {
        int bl = i*16 + ((ln >> 4) << 2) + r;
        pv[i*4+r] = bf2f(P[(size_t)(tl*128 + rblk*32 + bl)*4096 + (wv << 10) + cblk*16 + (ln & 15)]);
      }
  };

#define ISSUE(CK, SRC)                                                           \
  {                                                                              \
    const u64* q0_ = (SRC) + ab0 + (CK)*64;                                      \
    const u64* q1_ = (SRC) + ab1 + (CK)*64;                                      \
    _Pragma("unroll")                                                            \
    for (int i_ = 0; i_ < 4; ++i_) {                                             \
      sv[(CK) % 3][i_]     = __hip_atomic_load(q0_ + i_, __ATOMIC_RELAXED, __HIP_MEMORY_SCOPE_AGENT); \
      sv[(CK) % 3][4 + i_] = __hip_atomic_load(q1_ + i_, __ATOMIC_RELAXED, __HIP_MEMORY_SCOPE_AGENT); \
    }                                                                            \
  }

#define VW(CK)                                                                   \
  {                                                                              \
    u64* s8_ = sv[(CK) % 3];                                                     \
    for (;;) {                                                                   \
      bool ok_ = ((unsigned)(s8_[0] >> 32) == genr) &&                           \
                 ((unsigned)(s8_[1] >> 32) == genr) &&                           \
                 ((unsigned)(s8_[2] >> 32) == genr) &&                           \
                 ((unsigned)(s8_[3] >> 32) == genr) &&                           \
                 ((unsigned)(s8_[4] >> 32) == genr) &&                           \
                 ((unsigned)(s8_[5] >> 32) == genr) &&                           \
                 ((unsigned)(s8_[6] >> 32) == genr) &&                           \
                 ((unsigned)(s8_[7] >> 32) == genr);                             \
      if (__all(ok_)) break;                                                     \
      const u64* q0_ = hxcur + ab0 + (CK)*64;                                    \
      const u64* q1_ = hxcur + ab1 + (CK)*64;                                    \
      _Pragma("unroll")                                                          \
      for (int i_ = 0; i_ < 4; ++i_) {                                           \
        s8_[i_]     = __hip_atomic_load(q0_ + i_, __ATOMIC_RELAXED, __HIP_MEMORY_SCOPE_AGENT); \
        s8_[4 + i_] = __hip_atomic_load(q1_ + i_, __ATOMIC_RELAXED, __HIP_MEMORY_SCOPE_AGENT); \
      }                                                                          \
      __builtin_amdgcn_s_sleep(1);                                               \
    }                                                                            \
    uint4 w0_, w1_;                                                              \
    w0_.x = (unsigned)s8_[0]; w0_.y = (unsigned)s8_[1];                          \
    w0_.z = (unsigned)s8_[2]; w0_.w = (unsigned)s8_[3];                          \
    w1_.x = (unsigned)s8_[4]; w1_.y = (unsigned)s8_[5];                          \
    w1_.z = (unsigned)s8_[6]; w1_.w = (unsigned)s8_[7];                          \
    *(uint4*)&Ar[((CK) & 3)*4096 + ldo0] = w0_;                                  \
    *(uint4*)&Ar[((CK) & 3)*4096 + ldo1] = w1_;                                  \
  }

#define COMPUTE_CK(CK)                                                           \
  {                                                                              \
    const int aslot = (CK) & 3;                                                  \
    _Pragma("unroll")                                                            \
    for (int k4 = 0; k4 < 4; ++k4) {                                             \
      int s = k4*4 + (ln >> 4);                                                  \
      int ar0 = ln & 15, ar1 = 16 + (ln & 15);                                   \
      int brow = wv*16 + (ln & 15);                                              \
      bf16x8 a0 = *(const bf16x8*)&Ar[aslot*4096 + ar0*128 + ((s ^ (ar0 & 7)) << 3)]; \
      bf16x8 a1 = *(const bf16x8*)&Ar[aslot*4096 + ar1*128 + ((s ^ (ar1 & 7)) << 3)]; \
      bf16x8 bb = *(const bf16x8*)&Ul[(CK)*8192 + brow*128 + ((s ^ (brow & 7)) << 3)]; \
      acc0 = __builtin_amdgcn_mfma_f32_16x16x32_bf16(a0, bb, acc0, 0, 0, 0);     \
      acc1 = __builtin_amdgcn_mfma_f32_16x16x32_bf16(a1, bb, acc1, 0, 0, 0);     \
    }                                                                            \
  }

#define SCK(CK, DOISS)                                                           \
  VW(CK)                                                                         \
  if (DOISS) ISSUE((CK)+3, hxcur)                                                \
  asm volatile("s_waitcnt lgkmcnt(0)" ::: "memory");                             \
  __builtin_amdgcn_sched_barrier(0);                                             \
  __builtin_amdgcn_s_barrier();                                                  \
  COMPUTE_CK(CK)

  u64 sv[3][8];
  const u64* hxcur = hx2 + (size_t)(t0 % 3)*HXATOMS;
  float pv[8];
  load_pv(0, pv);
  ISSUE(0, hxcur) ISSUE(1, hxcur) ISSUE(2, hxcur)

  for (int tl = 0; tl < CHUNK; ++tl) {
    const int t = t0 + tl;
    const unsigned genr = (unsigned)t;
    u64* hxW2 = hx2 + (size_t)((t + 1) % 3)*HXATOMS;

    f32x4 acc0 = {}, acc1 = {};
    SCK(0,1) SCK(1,1) SCK(2,1) SCK(3,1) SCK(4,1)
    SCK(5,0) SCK(6,0) SCK(7,0)

    // ---- epilogue: inner sigmoid -> cross-gate exchange via sm (slot0 free now)
    #pragma unroll
    for (int i = 0; i < 2; ++i)
      #pragma unroll
      for (int r = 0; r < 4; ++r) {
        int bl = i*16 + ((ln >> 4) << 2) + r;
        float v = (i ? acc1[r] : acc0[r]) + pv[i*4+r];
        sm[wv*512 + bl*16 + (ln & 15)] = sigm(v);
      }
    __syncthreads();
    float2 h2;
    {
      const float2* sm2 = (const float2*)sm;
      int e = b_loc*8 + (j0 >> 1);
      float2 sF = sm2[0*256 + e], sI = sm2[1*256 + e];
      float2 sG = sm2[2*256 + e], sO = sm2[3*256 + e];
      float f0 = sigm(sF.x), i0 = sigm(sI.x), g0 = ftanh(sG.x), o0 = sigm(sO.x);
      float f1 = sigm(sF.y), i1 = sigm(sI.y), g1 = ftanh(sG.y), o1 = sigm(sO.y);
      float cn0 = f0*cxr.x + i0*g0, cn1 = f1*cxr.y + i1*g1;
      float h0 = o0*ftanh(cn0),     h1 = o1*ftanh(cn1);
      cxr.x = cn0; cxr.y = cn1;
      h2.x = h0; h2.y = h1;
      unsigned hp = (unsigned)f2bf(h0) | ((unsigned)f2bf(h1) << 16);
      u64 pk = (u64)hp | ((u64)(unsigned)(t + 1) << 32);
      __hip_atomic_store(hxW2 + catom, pk,
                         __ATOMIC_RELAXED, __HIP_MEMORY_SCOPE_AGENT);
    }
    *(float2*)&outc[(size_t)tl*BH + ci] = h2;

    if (tl != CHUNK - 1) {
      float pvn[8];
      load_pv(tl + 1, pvn);                 // P loads oldest in queue
      hxcur = hx2 + (size_t)((t + 1) % 3)*HXATOMS;
      ISSUE(0, hxcur) ISSUE(1, hxcur) ISSUE(2, hxcur)
      #pragma unroll
      for (int q = 0; q < 8; ++q) pv[q] = pvn[q];  // waits P only (FIFO)
    }
    __syncthreads();   // protect sm/slot0 before next step's VW(0)
  }
  *(float2*)&cxg[ci] = cxr;
#undef ISSUE
#undef VW
#undef COMPUTE_CK
#undef SCK
}

extern "C" void kernel_launch(void* const* d_in, const int* in_sizes, int n_in,
                              void* d_out, int out_size, void* d_ws, size_t ws_size,
                              hipStream_t stream) {
  const float* x  = (const float*)d_in[0];   // (512,128,1024)
  const float* pW = (const float*)d_in[1];   // (4096,2048)
  const float* pb = (const float*)d_in[2];   // (4096)
  const float* qW = (const float*)d_in[3];   // (1024,1024)
  float* out = (float*)d_out;

  char* w = (char*)d_ws;
  auto carve = [&](size_t bytes) { char* p = w; w += (bytes + 255) & ~(size_t)255; return p; };
  ushort_t* qWbf = (ushort_t*)carve((size_t)HID*HID*2);
  ushort_t* pWt  = (ushort_t*)carve((size_t)2048*4096*2);
  ushort_t* W2   = (ushort_t*)carve((size_t)4096*2048*2);
  float*    b2   = (float*)   carve((size_t)4096*4);
  u64*      hx2  = (u64*)     carve((size_t)3*HXATOMS*8);       // 1.5 MB
  float*    cxws = (float*)   carve((size_t)BH*4);
  ushort_t* xbf  = (ushort_t*)carve((size_t)CHUNK*BATCH*HID*2);
  ushort_t* Pc   = (ushort_t*)carve((size_t)CHUNK*BATCH*G4*2);

  (void)hipFuncSetAttribute((const void*)qlstm_scan,
                            hipFuncAttributeMaxDynamicSharedMemorySize, SCAN_LDS);
  (void)hipFuncSetAttribute((const void*)gemm256,
                            hipFuncAttributeMaxDynamicSharedMemorySize, GEMM256_LDS);

  // weight folding
  cast_f32_bf16<<<(HID*HID/4 + 255)/256, 256, 0, stream>>>(qW, qWbf, HID*HID/4);
  transpose_cast<<<dim3(64, 128), 256, 0, stream>>>(pW, pWt);
  bias_fold<<<4096, 64, 0, stream>>>(qW, pb, b2);
  gemm128<<<dim3(16, 32), 256, 0, stream>>>(qWbf, 1024, 1023u, pWt, 4096, ~1023u, nullptr, W2, 2048, 1024);

  hipMemsetAsync(hx2, 0, (size_t)HXATOMS*8, stream);   // buf0: h=0, tag=0 (= t0)
  hipMemsetAsync(cxws, 0, (size_t)BH*4, stream);

  for (int c = 0; c < SEQ/CHUNK; ++c) {
    cast_f32_bf16<<<(CHUNK*BATCH*HID/4 + 255)/256, 256, 0, stream>>>(
        x + (size_t)c*CHUNK*BATCH*HID, xbf, CHUNK*BATCH*HID/4);
    gemm256<<<dim3(G4/256, CHUNK*BATCH/256), 512, GEMM256_LDS, stream>>>(
        xbf, W2, b2, Pc);

    const ushort_t* Pa = Pc; const ushort_t* W2a = W2;
    u64* hxa = hx2; float* cxa = cxws;
    float* outa = out + (size_t)c*CHUNK*BH;
    int t0 = c*CHUNK;
    void* args[6] = { &Pa, &W2a, &hxa, &cxa, &outa, &t0 };
    hipLaunchCooperativeKernel((const void*)qlstm_scan, dim3(NBLK), dim3(256),
                               args, SCAN_LDS, stream);
  }
  hipMemcpyAsync(out + (size_t)SEQ*BH,      out + (size_t)(SEQ-1)*BH, (size_t)BH*4,
                 hipMemcpyDeviceToDevice, stream);
  hipMemcpyAsync(out + (size_t)SEQ*BH + BH, cxws, (size_t)BH*4,
                 hipMemcpyDeviceToDevice, stream);
}

// Round 14
// 2979.790 us; speedup vs baseline: 2.2489x; 2.2489x over previous
//
#include <hip/hip_runtime.h>

typedef unsigned short ushort_t;
typedef __attribute__((ext_vector_type(4))) float f32x4;
typedef __attribute__((ext_vector_type(8))) __bf16 bf16x8;

#define SEQ   512
#define BATCH 128
#define HID   1024
#define G4    4096
#define CHUNK 64
#define BH    (BATCH*HID)
#define NBLK  256
#define FLAG_STRIDE 32
#define SCAN_LDS (131072 + 32768)
#define GEMM256_LDS 131072

__device__ __forceinline__ ushort_t f2bf(float f) {
  unsigned u = __float_as_uint(f);
  u += 0x7FFFu + ((u >> 16) & 1u);         // RNE
  return (ushort_t)(u >> 16);
}
__device__ __forceinline__ float bf2f(ushort_t h) {
  return __uint_as_float(((unsigned)h) << 16);
}
__device__ __forceinline__ float sigm(float x) { return 1.0f / (1.0f + __expf(-x)); }
__device__ __forceinline__ float ftanh(float x) {
  float xc = fminf(fmaxf(x, -15.f), 15.f);
  float t = __expf(2.f * xc);
  return (t - 1.f) / (t + 1.f);
}

__device__ __forceinline__ void lds16(const ushort_t* g, ushort_t* l) {
  __builtin_amdgcn_global_load_lds(
      (const __attribute__((address_space(1))) unsigned int*)g,
      (__attribute__((address_space(3))) unsigned int*)l, 16, 0, 0);
}
// coherent (SC0|SC1): read at coherence point -> no acquire fence needed
__device__ __forceinline__ void lds16c(const ushort_t* g, ushort_t* l) {
  __builtin_amdgcn_global_load_lds(
      (const __attribute__((address_space(1))) unsigned int*)g,
      (__attribute__((address_space(3))) unsigned int*)l, 16, 0, 0x11);
}

// ---------------- casts ----------------
__global__ void cast_f32_bf16(const float* __restrict__ in, ushort_t* __restrict__ out, int n4) {
  int i = blockIdx.x * blockDim.x + threadIdx.x;
  if (i < n4) {
    float4 v = ((const float4*)in)[i];
    union { ushort_t u[4]; uint2 v2; } o;
    o.u[0] = f2bf(v.x); o.u[1] = f2bf(v.y); o.u[2] = f2bf(v.z); o.u[3] = f2bf(v.w);
    ((uint2*)out)[i] = o.v2;
  }
}

__global__ __launch_bounds__(256) void transpose_cast(const float* __restrict__ pw, ushort_t* __restrict__ pwt) {
  __shared__ float tile[32][33];
  int bx = blockIdx.x, by = blockIdx.y;
  int tx = threadIdx.x & 31, ty = threadIdx.x >> 5;
  for (int i = 0; i < 32; i += 8)
    tile[ty + i][tx] = pw[(size_t)(by*32 + ty + i)*2048 + bx*32 + tx];
  __syncthreads();
  for (int i = 0; i < 32; i += 8) {
    int r = ty + i;
    pwt[(size_t)(bx*32 + r)*4096 + by*32 + tx] = f2bf(tile[tx][r]);
  }
}

__global__ void bias_fold(const float* __restrict__ qW, const float* __restrict__ pb, float* __restrict__ b2) {
  int r = blockIdx.x;
  int j = r & (HID-1), gb = r & ~(HID-1);
  float s = 0.f;
  for (int k = threadIdx.x; k < HID; k += 64)
    s += qW[(size_t)j*HID + k] * pb[gb + k];
  for (int off = 32; off; off >>= 1) s += __shfl_down(s, off, 64);
  if (threadIdx.x == 0) b2[r] = s;
}

// ---------------- 128x128 bf16 GEMM (m97 structure) — weight fold only
__global__ __launch_bounds__(256) void gemm128(
    const ushort_t* __restrict__ A, int lda, unsigned arow_mask,
    const ushort_t* __restrict__ B, int ldb, unsigned bko_mask,
    const float* __restrict__ bias, ushort_t* __restrict__ C, int ldc, int K)
{
  __shared__ __align__(16) ushort_t Al[128*64];
  __shared__ __align__(16) ushort_t Bl[128*64];
  const int tid = threadIdx.x, wv = tid >> 6, ln = tid & 63;
  const int bn = blockIdx.x, bm = blockIdx.y;
  const int bko = (int)(((unsigned)(bm << 7)) & bko_mask);
  const int m0 = (wv & 1) << 6, n0 = (wv >> 1) << 6;
  f32x4 acc[4][4] = {};
  for (int k0 = 0; k0 < K; k0 += 64) {
    for (int rr = 0; rr < 4; ++rr) {
      int r0 = (rr << 5) + (wv << 3);
      unsigned ga = ((unsigned)((bm << 7) + r0 + (ln >> 3))) & arow_mask;
      lds16(A + (size_t)ga*lda + k0 + ((ln & 7) << 3), &Al[r0 << 6]);
      unsigned gbr = (unsigned)((bn << 7) + r0 + (ln >> 3));
      lds16(B + (size_t)gbr*ldb + bko + k0 + ((ln & 7) << 3), &Bl[r0 << 6]);
    }
    __syncthreads();
    for (int kk = 0; kk < 64; kk += 32) {
      const int lrow = ln & 15, lk = kk + ((ln >> 4) << 3);
      bf16x8 af[4], bfr[4];
      for (int i = 0; i < 4; ++i) af[i]  = *(const bf16x8*)&Al[((m0 + (i << 4) + lrow) << 6) + lk];
      for (int j = 0; j < 4; ++j) bfr[j] = *(const bf16x8*)&Bl[((n0 + (j << 4) + lrow) << 6) + lk];
      for (int i = 0; i < 4; ++i)
        for (int j = 0; j < 4; ++j)
          acc[i][j] = __builtin_amdgcn_mfma_f32_16x16x32_bf16(af[i], bfr[j], acc[i][j], 0, 0, 0);
    }
    __syncthreads();
  }
  for (int i = 0; i < 4; ++i)
    for (int j = 0; j < 4; ++j) {
      int col = (bn << 7) + n0 + (j << 4) + (ln & 15);
      float bv = bias ? bias[col] : 0.f;
      for (int r = 0; r < 4; ++r) {
        int row = (bm << 7) + m0 + (i << 4) + ((ln >> 4) << 2) + r;
        C[(size_t)row*ldc + col] = f2bf(acc[i][j][r] + bv);
      }
    }
}

// ---------------- 256x256 8-phase bf16 GEMM: P = x @ V^T + b2 ----------------
// r6-verified body + T1 bijective XCD swizzle (512 WGs, 512%8==0).
__global__ __launch_bounds__(512) void gemm256(
    const ushort_t* __restrict__ A, const ushort_t* __restrict__ B,
    const float* __restrict__ bias, ushort_t* __restrict__ C)
{
  extern __shared__ __align__(16) ushort_t lds[];
  ushort_t* LA = lds;
  ushort_t* LB = lds + 32768;
  const int tid = threadIdx.x, wv8 = tid >> 6, ln = tid & 63;
  const int wm = wv8 >> 2, wn = wv8 & 3;
  // XCD swizzle: dispatch order is x-major; give each XCD a contiguous chunk.
  const int flat = blockIdx.y * gridDim.x + blockIdx.x;     // 0..511
  const int swz  = ((flat & 7) << 6) | (flat >> 3);          // bijective
  const int bn = swz & 15, bm = swz >> 4;
  const int lr = ln & 15, lg = ln >> 4;

  f32x4 acc[8][4] = {};
  bf16x8 af[4][2], bfr[4][2];

  auto stA = [&](int db, int half, int kt) {
    ushort_t* d = LA + db*16384 + half*8192 + (wv8 << 9);
    const int ce = ((ln & 7) ^ (ln >> 3)) << 3;
    #pragma unroll
    for (int p = 0; p < 2; ++p) {
      int rr = half*128 + p*64 + (wv8 << 3) + (ln >> 3);
      lds16(A + (size_t)(bm*256 + rr)*1024 + kt*64 + ce, d + p*4096);
    }
  };
  auto stB = [&](int db, int half, int kt) {
    ushort_t* d = LB + db*16384 + half*8192 + (wv8 << 9);
    const int ce = ((ln & 7) ^ (ln >> 3)) << 3;
    #pragma unroll
    for (int p = 0; p < 2; ++p) {
      int rr = half*128 + p*64 + (wv8 << 3) + (ln >> 3);
      lds16(B + (size_t)(bn*256 + rr)*2048 + kt*64 + ce, d + p*4096);
    }
  };

#define RD_A(DB, MQ) { _Pragma("unroll") for (int i_ = 0; i_ < 4; ++i_) { \
    const int row_ = ((MQ)*4 + i_)*16 + lr; \
    const ushort_t* b_ = &LA[(DB)*16384 + wm*8192 + row_*64]; \
    af[i_][0] = *(const bf16x8*)&b_[ (lg << 3)       ^ ((lr & 7) << 3)]; \
    af[i_][1] = *(const bf16x8*)&b_[((lg << 3) | 32) ^ ((lr & 7) << 3)]; } }

#define RD_B(DB, NQ) { _Pragma("unroll") for (int j_ = 0; j_ < 2; ++j_) { \
    const int row_ = (wn & 1)*64 + ((NQ)*2 + j_)*16 + lr; \
    const ushort_t* b_ = &LB[(DB)*16384 + (wn >> 1)*8192 + row_*64]; \
    bfr[(NQ)*2 + j_][0] = *(const bf16x8*)&b_[ (lg << 3)       ^ ((lr & 7) << 3)]; \
    bfr[(NQ)*2 + j_][1] = *(const bf16x8*)&b_[((lg << 3) | 32) ^ ((lr & 7) << 3)]; } }

#define QUAD(MQ, NQ) \
  __builtin_amdgcn_s_setprio(1); \
  { _Pragma("unroll") for (int i_ = 0; i_ < 4; ++i_) \
      _Pragma("unroll") for (int j_ = 0; j_ < 2; ++j_) \
        _Pragma("unroll") for (int k_ = 0; k_ < 2; ++k_) \
          acc[(MQ)*4 + i_][(NQ)*2 + j_] = __builtin_amdgcn_mfma_f32_16x16x32_bf16( \
              af[i_][k_], bfr[(NQ)*2 + j_][k_], acc[(MQ)*4 + i_][(NQ)*2 + j_], 0, 0, 0); } \
  __builtin_amdgcn_s_setprio(0);

#define BAR() __builtin_amdgcn_s_barrier()
#define LGK0() do { asm volatile("s_waitcnt lgkmcnt(0)" ::: "memory"); \
                    __builtin_amdgcn_sched_barrier(0); } while (0)
#define VM4() do { asm volatile("s_waitcnt vmcnt(4)" ::: "memory"); \
                   __builtin_amdgcn_sched_barrier(0); } while (0)

  stA(0,0,0); stA(0,1,0); stB(0,0,0); stB(0,1,0); stB(1,0,1); stB(1,1,1);
  asm volatile("s_waitcnt vmcnt(4)" ::: "memory");
  BAR();

  for (int i = 0; i < 8; ++i) {
    const int k1 = 2*i + 1, k2 = 2*i + 2, k3 = 2*i + 3;
    RD_A(0,0); RD_B(0,0); stA(1,0,k1);            BAR(); LGK0(); QUAD(0,0); BAR();
    RD_B(0,1); stA(1,1,k1);                       BAR(); LGK0(); QUAD(0,1); BAR();
    RD_A(0,1); if (k2 < 16) stB(0,0,k2);          BAR(); LGK0(); QUAD(1,0); BAR();
    if (k2 < 16) stB(0,1,k2);                     BAR();         QUAD(1,1); VM4(); BAR();
    RD_A(1,0); RD_B(1,0); if (k2 < 16) stA(0,0,k2); BAR(); LGK0(); QUAD(0,0); BAR();
    RD_B(1,1); if (k2 < 16) stA(0,1,k2);          BAR(); LGK0(); QUAD(0,1); BAR();
    RD_A(1,1); if (k3 < 16) stB(1,0,k3);          BAR(); LGK0(); QUAD(1,0); BAR();
    if (k3 < 16) stB(1,1,k3);                     BAR();         QUAD(1,1); VM4(); BAR();
  }

  const int crow0 = bm*256 + wm*128;
  const int ccol0 = bn*256 + wn*64;
  #pragma unroll
  for (int m = 0; m < 8; ++m)
    #pragma unroll
    for (int n = 0; n < 4; ++n) {
      int col = ccol0 + n*16 + lr;
      float bv = bias[col];
      #pragma unroll
      for (int r = 0; r < 4; ++r) {
        int row = crow0 + m*16 + lg*4 + r;
        C[(size_t)row*4096 + col] = f2bf(acc[m][n][r] + bv);
      }
    }
#undef RD_A
#undef RD_B
#undef QUAD
#undef BAR
#undef LGK0
#undef VM4
}

// ---------------- persistent per-chunk scan kernel (r6-verified, unchanged) ----
__global__ __launch_bounds__(256, 1) void qlstm_scan(
    const ushort_t* __restrict__ P,
    const ushort_t* __restrict__ W2,
    ushort_t* __restrict__ hxb,
    float* __restrict__ cxg,
    float* __restrict__ outc,
    int t0,
    unsigned* __restrict__ flags)
{
  extern __shared__ __align__(16) ushort_t lds[];
  ushort_t* Ul = lds;
  ushort_t* Ar = lds + 65536;
  float*    sm = (float*)(lds + 65536);

  const int tid = threadIdx.x, wv = tid >> 6, ln = tid & 63;
  const int rblk = blockIdx.x & 3, cblk = blockIdx.x >> 2;
  unsigned* gflags = flags + (size_t)rblk*64*FLAG_STRIDE;

  for (int ck = 0; ck < 8; ++ck)
    for (int rr = 0; rr < 4; ++rr) {
      int lr = rr*16 + wv*4 + (ln >> 4);
      int grow = ((lr >> 4) << 10) + cblk*16 + (lr & 15);
      int gcol = ck*128 + (((ln & 15) ^ (lr & 7)) << 3);
      lds16(W2 + (size_t)grow*2048 + 1024 + gcol, &Ul[ck*8192 + (rr*16 + wv*4)*128]);
    }

  const int b_loc = tid >> 3;
  const int j0    = (tid & 7) << 1;
  const size_t ci = (size_t)(rblk*32 + b_loc)*1024 + cblk*16 + j0;
  float2 cxr = *(const float2*)&cxg[ci];

  auto stageA = [&](int slot, int k0, const ushort_t* hxR) {
    #pragma unroll
    for (int rr = 0; rr < 2; ++rr) {
      int row = rr*16 + wv*4 + (ln >> 4);
      int gcol = ((ln & 15) ^ (row & 7)) << 3;
      lds16c(hxR + (size_t)(rblk*32 + row)*1024 + k0 + gcol,
             &Ar[slot*4096 + (rr*16 + wv*4)*128]);
    }
  };
  auto load_pv = [&](int tl, float* pv) {
    #pragma unroll
    for (int i = 0; i < 2; ++i)
      #pragma unroll
      for (int r = 0; r < 4; ++r) {
        int bl = i*16 + ((ln >> 4) << 2) + r;
        pv[i*4+r] = bf2f(P[(size_t)(tl*128 + rblk*32 + bl)*4096 + (wv << 10) + cblk*16 + (ln & 15)]);
      }
  };

  float pv[8];
  load_pv(0, pv);

  for (int tl = 0; tl < CHUNK; ++tl) {
    const int t = t0 + tl;
    const ushort_t* hxR = hxb + (size_t)(t % 3)*BH;
    ushort_t*       hxW = hxb + (size_t)((t + 1) % 3)*BH;

    f32x4 acc0 = {}, acc1 = {};
    stageA(0, 0, hxR);
    stageA(1, 128, hxR);
    stageA(2, 256, hxR);

    #define COMPUTE_CK(CK)                                                         \
      {                                                                            \
        const int aslot = (CK) & 3;                                                \
        _Pragma("unroll")                                                          \
        for (int k4 = 0; k4 < 4; ++k4) {                                           \
          int s = k4*4 + (ln >> 4);                                                \
          int ar0 = ln & 15, ar1 = 16 + (ln & 15);                                 \
          int brow = wv*16 + (ln & 15);                                            \
          bf16x8 a0 = *(const bf16x8*)&Ar[aslot*4096 + ar0*128 + ((s ^ (ar0 & 7)) << 3)]; \
          bf16x8 a1 = *(const bf16x8*)&Ar[aslot*4096 + ar1*128 + ((s ^ (ar1 & 7)) << 3)]; \
          bf16x8 bb = *(const bf16x8*)&Ul[(CK)*8192 + brow*128 + ((s ^ (brow & 7)) << 3)]; \
          acc0 = __builtin_amdgcn_mfma_f32_16x16x32_bf16(a0, bb, acc0, 0, 0, 0);   \
          acc1 = __builtin_amdgcn_mfma_f32_16x16x32_bf16(a1, bb, acc1, 0, 0, 0);   \
        }                                                                          \
      }
    #define STEP_CK(CK, WN, DOSTAGE)                                               \
      asm volatile("s_waitcnt vmcnt(" #WN ")" ::: "memory");                       \
      __builtin_amdgcn_s_barrier();                                                \
      if (DOSTAGE) stageA(((CK)+3) & 3, ((CK)+3)*128, hxR);                        \
      COMPUTE_CK(CK)

    STEP_CK(0, 4, 1) STEP_CK(1, 4, 1) STEP_CK(2, 4, 1)
    STEP_CK(3, 4, 1) STEP_CK(4, 4, 1)
    STEP_CK(5, 4, 0) STEP_CK(6, 2, 0) STEP_CK(7, 0, 0)
    #undef STEP_CK
    #undef COMPUTE_CK

    #pragma unroll
    for (int i = 0; i < 2; ++i)
      #pragma unroll
      for (int r = 0; r < 4; ++r) {
        int bl = i*16 + ((ln >> 4) << 2) + r;
        float v = (i ? acc1[r] : acc0[r]) + pv[i*4+r];
        sm[wv*512 + bl*16 + (ln & 15)] = sigm(v);
      }
    __syncthreads();
    float2 h2;
    {
      const float2* sm2 = (const float2*)sm;
      int e = b_loc*8 + (j0 >> 1);
      float2 sF = sm2[0*256 + e], sI = sm2[1*256 + e];
      float2 sG = sm2[2*256 + e], sO = sm2[3*256 + e];
      float f0 = sigm(sF.x), i0 = sigm(sI.x), g0 = ftanh(sG.x), o0 = sigm(sO.x);
      float f1 = sigm(sF.y), i1 = sigm(sI.y), g1 = ftanh(sG.y), o1 = sigm(sO.y);
      float cn0 = f0*cxr.x + i0*g0, cn1 = f1*cxr.y + i1*g1;
      float h0 = o0*ftanh(cn0),     h1 = o1*ftanh(cn1);
      cxr.x = cn0; cxr.y = cn1;
      h2.x = h0; h2.y = h1;
      unsigned hp = (unsigned)f2bf(h0) | ((unsigned)f2bf(h1) << 16);
      __hip_atomic_store((unsigned*)&hxW[ci], hp,
                         __ATOMIC_RELAXED, __HIP_MEMORY_SCOPE_AGENT);
    }

    if (tl != CHUNK - 1) {
      const unsigned gen = (unsigned)(t + 1);
      asm volatile("s_waitcnt vmcnt(0)" ::: "memory");
      __syncthreads();
      if (tid == 0)
        __hip_atomic_store(gflags + (size_t)cblk*FLAG_STRIDE, gen,
                           __ATOMIC_RELAXED, __HIP_MEMORY_SCOPE_AGENT);
      *(float2*)&outc[(size_t)tl*BH + ci] = h2;
      float pvn[8];
      load_pv(tl + 1, pvn);
      if (tid < 64) {
        int it = 0;
        for (;;) {
          unsigned a = __hip_atomic_load(gflags + (size_t)tid*FLAG_STRIDE,
                                         __ATOMIC_RELAXED, __HIP_MEMORY_SCOPE_AGENT);
          if (__all(a >= gen)) break;
          if ((++it & 255) == 0) __builtin_amdgcn_fence(__ATOMIC_ACQUIRE, "agent");
          __builtin_amdgcn_s_sleep(1);
        }
      }
      __syncthreads();
      #pragma unroll
      for (int q = 0; q < 8; ++q) pv[q] = pvn[q];
    } else {
      *(float2*)&outc[(size_t)tl*BH + ci] = h2;
    }
  }
  *(float2*)&cxg[ci] = cxr;
}

extern "C" void kernel_launch(void* const* d_in, const int* in_sizes, int n_in,
                              void* d_out, int out_size, void* d_ws, size_t ws_size,
                              hipStream_t stream) {
  const float* x  = (const float*)d_in[0];   // (512,128,1024)
  const float* pW = (const float*)d_in[1];   // (4096,2048)
  const float* pb = (const float*)d_in[2];   // (4096)
  const float* qW = (const float*)d_in[3];   // (1024,1024)
  float* out = (float*)d_out;

  char* w = (char*)d_ws;
  auto carve = [&](size_t bytes) { char* p = w; w += (bytes + 255) & ~(size_t)255; return p; };
  ushort_t* qWbf = (ushort_t*)carve((size_t)HID*HID*2);
  ushort_t* pWt  = (ushort_t*)carve((size_t)2048*4096*2);
  ushort_t* W2   = (ushort_t*)carve((size_t)4096*2048*2);
  float*    b2   = (float*)   carve((size_t)4096*4);
  ushort_t* hxb  = (ushort_t*)carve((size_t)3*BH*2);
  float*    cxws = (float*)   carve((size_t)BH*4);
  unsigned* flags= (unsigned*)carve((size_t)NBLK*FLAG_STRIDE*4);
  ushort_t* xbf  = (ushort_t*)carve((size_t)CHUNK*BATCH*HID*2);
  ushort_t* Pc   = (ushort_t*)carve((size_t)CHUNK*BATCH*G4*2);

  (void)hipFuncSetAttribute((const void*)qlstm_scan,
                            hipFuncAttributeMaxDynamicSharedMemorySize, SCAN_LDS);
  (void)hipFuncSetAttribute((const void*)gemm256,
                            hipFuncAttributeMaxDynamicSharedMemorySize, GEMM256_LDS);

  // weight folding
  cast_f32_bf16<<<(HID*HID/4 + 255)/256, 256, 0, stream>>>(qW, qWbf, HID*HID/4);
  transpose_cast<<<dim3(64, 128), 256, 0, stream>>>(pW, pWt);
  bias_fold<<<4096, 64, 0, stream>>>(qW, pb, b2);
  gemm128<<<dim3(16, 32), 256, 0, stream>>>(qWbf, 1024, 1023u, pWt, 4096, ~1023u, nullptr, W2, 2048, 1024);

  hipMemsetAsync(hxb, 0, (size_t)BH*2, stream);        // h_{-1} = 0
  hipMemsetAsync(cxws, 0, (size_t)BH*4, stream);
  hipMemsetAsync(flags, 0, (size_t)NBLK*FLAG_STRIDE*4, stream);

  for (int c = 0; c < SEQ/CHUNK; ++c) {
    cast_f32_bf16<<<(CHUNK*BATCH*HID/4 + 255)/256, 256, 0, stream>>>(
        x + (size_t)c*CHUNK*BATCH*HID, xbf, CHUNK*BATCH*HID/4);
    gemm256<<<dim3(G4/256, CHUNK*BATCH/256), 512, GEMM256_LDS, stream>>>(
        xbf, W2, b2, Pc);

    const ushort_t* Pa = Pc; const ushort_t* W2a = W2;
    ushort_t* hxa = hxb; float* cxa = cxws;
    float* outa = out + (size_t)c*CHUNK*BH;
    int t0 = c*CHUNK; unsigned* fla = flags;
    void* args[7] = { &Pa, &W2a, &hxa, &cxa, &outa, &t0, &fla };
    hipLaunchCooperativeKernel((const void*)qlstm_scan, dim3(NBLK), dim3(256),
                               args, SCAN_LDS, stream);
  }
  hipMemcpyAsync(out + (size_t)SEQ*BH,      out + (size_t)(SEQ-1)*BH, (size_t)BH*4,
                 hipMemcpyDeviceToDevice, stream);
  hipMemcpyAsync(out + (size_t)SEQ*BH + BH, cxws, (size_t)BH*4,
                 hipMemcpyDeviceToDevice, stream);
}